// Round 10
// baseline (6011.954 us; speedup 1.0000x reference)
//
#include <hip/hip_runtime.h>
#include <hip/hip_bf16.h>

// Problem constants
#define B 128
#define T 256
#define E 300
#define HH 256
#define O 5
#define NSTEP (2*T - 1)   // 511
#define NINT 255          // internal (reduce) nodes per batch
#define NG 16             // nodes per group (weight amortization factor)
#define PSTR 81           // padded partial stride (5*NG + 1)
#define IOFF 16777216u    // internal[] offset from buffers base (B*T*512)
#define LMAX_DIRECT 176   // per-level launches cover 1..176; catch-all covers rest
#define CHUNK 96          // k_prep trans staging chunk
#define BAR_STRIDE 16
#define BAR_WORDS ((32 + 2) * BAR_STRIDE)

__device__ __forceinline__ float sigm(float x) { return 1.f / (1.f + __expf(-x)); }

// ---------------------------------------------------------------------------
// Hierarchical monotonic grid barrier (catch-all only; normally never runs).
// ---------------------------------------------------------------------------
__device__ __forceinline__ void grid_barrier(unsigned* bar, int myN) {
  __syncthreads();
  if (threadIdx.x == 0) {
    __threadfence();
    const int per_sub = (int)(gridDim.x >> 5);
    const int s = (int)(blockIdx.x & 31);
    unsigned r = atomicAdd(&bar[s * BAR_STRIDE], 1u);
    if (r == (unsigned)(myN * per_sub - 1)) {
      unsigned q = atomicAdd(&bar[32 * BAR_STRIDE], 1u);
      if (q == (unsigned)(myN * 32 - 1)) {
        atomicAdd(&bar[33 * BAR_STRIDE], 1u);
      }
    }
    while (__hip_atomic_load(&bar[33 * BAR_STRIDE], __ATOMIC_ACQUIRE,
                             __HIP_MEMORY_SCOPE_AGENT) < (unsigned)myN) {
      __builtin_amdgcn_s_sleep(2);
    }
    __threadfence();
  }
  __syncthreads();
}

// ---------------------------------------------------------------------------
// K0: weight prep.
//   WcT[e][0:256] = Wp[h][e], WcT[e][256:512] = Wg[h][e]
//   W4: float4-tiled Wr^T:  W4[((k>>2)*1280 + j)*4 + (k&3)] = Wr[j][k]
// ---------------------------------------------------------------------------
__global__ __launch_bounds__(256) void k_transpose(
    const float* __restrict__ Wp, const float* __restrict__ Wg,
    const float* __restrict__ Wr, float* __restrict__ WcT,
    float* __restrict__ W4) {
  int idx = blockIdx.x * 256 + threadIdx.x;
  if (idx < HH * E) {
    int h = idx / E;
    int e = idx % E;
    WcT[e * 512 + h]       = Wp[idx];
    WcT[e * 512 + 256 + h] = Wg[idx];
  }
  if (idx < 5 * HH * 2 * HH) {   // 1280*512
    int j = idx / 512;
    int k = idx % 512;
    W4[((size_t)(k >> 2) * 1280 + j) * 4 + (k & 3)] = Wr[idx];
  }
}

// ---------------------------------------------------------------------------
// K1: leaf states. buffers[b][t][0:256]=h, [256:512]=c
// ---------------------------------------------------------------------------
#define TT 16
__global__ __launch_bounds__(256) void k_buffers(
    const int* __restrict__ x_ids, const float* __restrict__ embed,
    const float* __restrict__ WcT, const float* __restrict__ bp,
    const float* __restrict__ bg, float* __restrict__ buffers) {
  __shared__ float lds[TT * E];
  const int b  = blockIdx.y;
  const int t0 = blockIdx.x * TT;
  const int tid = threadIdx.x;

  for (int i = tid; i < TT * E; i += 256) {
    int t = i / E;
    int e = i % E;
    int id = x_ids[b * T + t0 + t];
    lds[i] = embed[(size_t)id * E + e];
  }
  __syncthreads();

  const int h = tid;
  float accP[TT], accG[TT];
#pragma unroll
  for (int t = 0; t < TT; ++t) { accP[t] = bp[h]; accG[t] = bg[h]; }

  for (int e = 0; e < E; ++e) {
    float wp = WcT[e * 512 + h];
    float wg = WcT[e * 512 + 256 + h];
#pragma unroll
    for (int t = 0; t < TT; ++t) {
      float x = lds[t * E + e];
      accP[t] = fmaf(x, wp, accP[t]);
      accG[t] = fmaf(x, wg, accG[t]);
    }
  }

#pragma unroll
  for (int t = 0; t < TT; ++t) {
    float c  = accP[t];
    float hb = tanhf(c) * sigm(accG[t]);
    size_t base = ((size_t)b * T + t0 + t) * 512;
    buffers[base + h]       = hb;
    buffers[base + 256 + h] = c;
  }
}

// ---------------------------------------------------------------------------
// K2: prep — LDS-resident rewrite (round-8 counters: 567us, global-latency
// bound). Stack (u16) + levels (u8) + chunked trans all in 147KB dynamic LDS.
// 1 block, 128 threads. meta[b][r] = left | right<<9 | level<<18
// ---------------------------------------------------------------------------
__global__ __launch_bounds__(128) void k_prep(
    const int* __restrict__ trans, int* __restrict__ meta,
    int* __restrict__ levCnt, int* __restrict__ levOff, int* __restrict__ maxLevG,
    int* __restrict__ rootA, unsigned* __restrict__ worklist,
    unsigned* __restrict__ bar) {
  extern __shared__ char dynls[];
  unsigned short* stkL = (unsigned short*)dynls;                 // [256][128] 64KB
  unsigned char*  levL = (unsigned char*)(dynls + 65536);        // [255][128] 32640B
  int*            tch  = (int*)(dynls + 65536 + 32640);          // [CHUNK][128] 48KB
  __shared__ int cnt[256];
  __shared__ int off[256];
  __shared__ int cur[256];
  const int b = threadIdx.x;
  for (int i = b; i < 256; i += 128) cnt[i] = 0;
  for (int i = b; i < BAR_WORDS; i += 128) bar[i] = 0u;
  __syncthreads();

  int sp = 0, bp = T, r = 0;
  for (int c0 = 0; c0 < NSTEP; c0 += CHUNK) {
    const int cend = min(NSTEP - c0, CHUNK);
    __syncthreads();                         // prior chunk consumed
    for (int i = b; i < cend * 128; i += 128) tch[i] = trans[c0 * 128 + i];
    __syncthreads();
    for (int s = 0; s < cend; ++s) {
      int tr = tch[s * 128 + b];
      if (tr == 0) {                         // SHIFT
        stkL[sp * 128 + b] = (unsigned short)(bp - 1);
        sp++; bp--;
      } else {                               // REDUCE
        int idR = stkL[(sp - 1) * 128 + b];
        int idL = stkL[(sp - 2) * 128 + b];
        sp -= 2;
        int lL = (idL < 256) ? 0 : (int)levL[(idL - 256) * 128 + b];
        int lR = (idR < 256) ? 0 : (int)levL[(idR - 256) * 128 + b];
        int lev = max(lL, lR) + 1;
        levL[r * 128 + b] = (unsigned char)lev;
        meta[b * NINT + r] = idL | (idR << 9) | (lev << 18);   // fire-and-forget
        atomicAdd(&cnt[lev], 1);
        stkL[sp * 128 + b] = (unsigned short)(256 + r);
        sp++; r++;
      }
    }
  }
  rootA[b] = (int)stkL[0 * 128 + b];
  __syncthreads();

  if (b == 0) {
    int acc = 0, ml = 1;
    for (int l = 0; l < 256; ++l) {
      off[l] = acc; acc += cnt[l];
      if (cnt[l] > 0) ml = l;
    }
    *maxLevG = ml;
  }
  __syncthreads();
  for (int i = b; i < 256; i += 128) { levCnt[i] = cnt[i]; levOff[i] = off[i]; cur[i] = off[i]; }
  __syncthreads();

  for (int i = 0; i < NINT; ++i) {
    int lev = (int)levL[i * 128 + b];
    int pos = atomicAdd(&cur[lev], 1);
    worklist[pos] = (unsigned)((b << 9) | (256 + i));
  }
}

// ---------------------------------------------------------------------------
// Level body. NG=16 nodes/group (2x weight-traffic amortization vs r8).
// Item = (group, 64-col h-slice); thread (hcol=tid&63, kq=tid>>6).
// States addressed as u32 dword offsets from `states` base (buffers;
// internal at +IOFF) -> offsets live in SGPRs via readfirstlane.
// ---------------------------------------------------------------------------
__device__ __forceinline__ void do_level(
    int cnt, int woff,
    const float* __restrict__ W4, const float* __restrict__ br,
    const int* __restrict__ meta, const unsigned* __restrict__ worklist,
    float* __restrict__ states, float* smem) {
  const int tid  = threadIdx.x;
  const int hcol = tid & 63;
  const int kq   = tid >> 6;

  const int ngrp = (cnt + NG - 1) / NG;
  const int items = ngrp << 2;

  for (int item = blockIdx.x; item < items; item += gridDim.x) {
    const int grp = item >> 2;
    const int h0  = (item & 3) << 6;
    __syncthreads();   // prior item's LDS reads complete before restage

    // --- node meta -> uniform u32 state offsets (SGPRs) ---
    unsigned offL[NG], offR[NG], offD[NG];
#pragma unroll
    for (int n = 0; n < NG; ++n) {
      int wi = woff + grp * NG + n;
      if (wi >= woff + cnt) wi = woff + cnt - 1;     // pad: duplicate last node
      unsigned w = worklist[wi];
      int node = __builtin_amdgcn_readfirstlane((int)(w & 511u));
      int bb   = __builtin_amdgcn_readfirstlane((int)(w >> 9));
      int m    = __builtin_amdgcn_readfirstlane(meta[bb * NINT + node - 256]);
      int il = m & 511, ir = (m >> 9) & 511;
      offL[n] = (il < 256) ? ((unsigned)(bb * T + il) << 9)
                           : (IOFF + ((unsigned)(bb * NINT + il - 256) << 9));
      offR[n] = (ir < 256) ? ((unsigned)(bb * T + ir) << 9)
                           : (IOFF + ((unsigned)(bb * NINT + ir - 256) << 9));
      offD[n] = IOFF + ((unsigned)(bb * NINT + node - 256) << 9);
    }

    // --- stage x = [hl | hr] into LDS (coalesced) ---
    float* xs = smem;                                // [NG][512]
#pragma unroll
    for (int n = 0; n < NG; ++n) {
      xs[n * 512 + tid]       = states[(size_t)offL[n] + tid];
      xs[n * 512 + 256 + tid] = states[(size_t)offR[n] + tid];
    }
    __syncthreads();

    // --- FMA over this thread's k-quarter (coalesced float4 weights) ---
    float a0[NG], a1[NG], a2[NG], a3[NG], a4[NG];
#pragma unroll
    for (int n = 0; n < NG; ++n) { a0[n]=0.f; a1[n]=0.f; a2[n]=0.f; a3[n]=0.f; a4[n]=0.f; }

    const float4* W4v = (const float4*)W4;
    const int jb = h0 + hcol;
    const int k4end = (kq << 5) + 32;
    for (int k4 = kq << 5; k4 < k4end; ++k4) {       // k = 4*k4
      const size_t kb4 = (size_t)k4 * 1280 + jb;
      float4 w0 = W4v[kb4];
      float4 w1 = W4v[kb4 + 256];
      float4 w2 = W4v[kb4 + 512];
      float4 w3 = W4v[kb4 + 768];
      float4 w4 = W4v[kb4 + 1024];
#pragma unroll
      for (int n = 0; n < NG; ++n) {
        float4 xv = *(const float4*)&xs[n * 512 + (k4 << 2)];
        float s0 = a0[n], s1 = a1[n], s2 = a2[n], s3 = a3[n], s4 = a4[n];
        s0 = fmaf(w0.x, xv.x, s0); s0 = fmaf(w0.y, xv.y, s0);
        s0 = fmaf(w0.z, xv.z, s0); s0 = fmaf(w0.w, xv.w, s0);
        s1 = fmaf(w1.x, xv.x, s1); s1 = fmaf(w1.y, xv.y, s1);
        s1 = fmaf(w1.z, xv.z, s1); s1 = fmaf(w1.w, xv.w, s1);
        s2 = fmaf(w2.x, xv.x, s2); s2 = fmaf(w2.y, xv.y, s2);
        s2 = fmaf(w2.z, xv.z, s2); s2 = fmaf(w2.w, xv.w, s2);
        s3 = fmaf(w3.x, xv.x, s3); s3 = fmaf(w3.y, xv.y, s3);
        s3 = fmaf(w3.z, xv.z, s3); s3 = fmaf(w3.w, xv.w, s3);
        s4 = fmaf(w4.x, xv.x, s4); s4 = fmaf(w4.y, xv.y, s4);
        s4 = fmaf(w4.z, xv.z, s4); s4 = fmaf(w4.w, xv.w, s4);
        a0[n] = s0; a1[n] = s1; a2[n] = s2; a3[n] = s3; a4[n] = s4;
      }
    }
    __syncthreads();   // xs dead; smem becomes partial buffer

    // --- k-split reduce: kq>=1 deposit partials ---
    if (kq >= 1) {
      float* pp = smem + (kq - 1) * (64 * PSTR) + hcol * PSTR;
#pragma unroll
      for (int n = 0; n < NG; ++n) {
        pp[n]          = a0[n];
        pp[NG + n]     = a1[n];
        pp[2 * NG + n] = a2[n];
        pp[3 * NG + n] = a3[n];
        pp[4 * NG + n] = a4[n];
      }
    }
    __syncthreads();

    // --- combine: kq==0 finishes its column for all NG nodes ---
    if (kq == 0) {
      const int habs = h0 + hcol;
      const float b0 = br[habs];
      const float b1 = br[256 + habs];
      const float b2 = br[512 + habs];
      const float b3 = br[768 + habs];
      const float b4 = br[1024 + habs];
#pragma unroll
      for (int n = 0; n < NG; ++n) {
        const float* q0 = smem + 0 * (64 * PSTR) + hcol * PSTR;
        const float* q1 = smem + 1 * (64 * PSTR) + hcol * PSTR;
        const float* q2 = smem + 2 * (64 * PSTR) + hcol * PSTR;
        float p0 = a0[n] + q0[n]          + q1[n]          + q2[n]          + b0;
        float p1 = a1[n] + q0[NG + n]     + q1[NG + n]     + q2[NG + n]     + b1;
        float p2 = a2[n] + q0[2 * NG + n] + q1[2 * NG + n] + q2[2 * NG + n] + b2;
        float p3 = a3[n] + q0[3 * NG + n] + q1[3 * NG + n] + q2[3 * NG + n] + b3;
        float p4 = a4[n] + q0[4 * NG + n] + q1[4 * NG + n] + q2[4 * NG + n] + b4;
        float cl = states[(size_t)offL[n] + 256 + habs];
        float cr = states[(size_t)offR[n] + 256 + habs];
        float ci  = sigm(p0);
        float cfl = sigm(p1);
        float cfr = sigm(p2);
        float tg  = tanhf(p3);
        float co  = sigm(p4);
        float cn  = ci * tg + cfl * cl + cfr * cr;
        float hn  = co * tanhf(cn);
        states[(size_t)offD[n] + habs]       = hn;   // dup-pad rewrites same value
        states[(size_t)offD[n] + 256 + habs] = cn;
      }
    }
  }
}

// ---------------------------------------------------------------------------
// K3a: one launch per level. Levels beyond maxLev exit immediately.
// ---------------------------------------------------------------------------
__global__ __launch_bounds__(256, 2) void k_level(
    int lev, const float* __restrict__ W4, const float* __restrict__ br,
    const int* __restrict__ meta, const int* __restrict__ levCnt,
    const int* __restrict__ levOff, const int* __restrict__ maxLevG,
    const unsigned* __restrict__ worklist, float* __restrict__ states) {
  __shared__ float smem[3 * 64 * PSTR];   // 62208 B (union: xs 32KB / partials)
  if (lev > *maxLevG) return;
  const int cnt = levCnt[lev];
  if (cnt == 0) return;
  do_level(cnt, levOff[lev], W4, br, meta, worklist, states, smem);
}

// ---------------------------------------------------------------------------
// K3b: cooperative catch-all for levels LMAX_DIRECT+1..maxLev (normally a
// no-op: expected maxLev ~100-120 < 176).
// ---------------------------------------------------------------------------
__global__ __launch_bounds__(256, 2) void k_catchall(
    const float* __restrict__ W4, const float* __restrict__ br,
    const int* __restrict__ meta, const int* __restrict__ levCnt,
    const int* __restrict__ levOff, const int* __restrict__ maxLevG,
    const unsigned* __restrict__ worklist, float* __restrict__ states,
    unsigned* __restrict__ bar) {
  __shared__ float smem[3 * 64 * PSTR];
  const int maxLev = *maxLevG;
  if (maxLev <= LMAX_DIRECT) return;
  for (int lev = LMAX_DIRECT + 1; lev <= maxLev; ++lev) {
    do_level(levCnt[lev], levOff[lev], W4, br, meta, worklist, states, smem);
    grid_barrier(bar, lev - LMAX_DIRECT);
  }
}

// ---------------------------------------------------------------------------
// K4: logits = root_h @ Wo^T + bo
// ---------------------------------------------------------------------------
__global__ __launch_bounds__(256) void k_out(
    const float* __restrict__ Wo, const float* __restrict__ bo,
    const int* __restrict__ rootA, const float* __restrict__ states,
    float* __restrict__ out) {
  const int b = blockIdx.x;
  const int tid = threadIdx.x;
  __shared__ float red[256];
  int rid = rootA[b];
  unsigned hoff = (rid < 256) ? ((unsigned)(b * T + rid) << 9)
                              : (IOFF + ((unsigned)(b * NINT + rid - 256) << 9));
  float hj = states[(size_t)hoff + tid];
  for (int m = 0; m < O; ++m) {
    red[tid] = Wo[m * HH + tid] * hj;
    __syncthreads();
    for (int off = 128; off > 0; off >>= 1) {
      if (tid < off) red[tid] += red[tid + off];
      __syncthreads();
    }
    if (tid == 0) out[b * O + m] = red[0] + bo[m];
    __syncthreads();
  }
}

// ---------------------------------------------------------------------------
extern "C" void kernel_launch(void* const* d_in, const int* in_sizes, int n_in,
                              void* d_out, int out_size, void* d_ws, size_t ws_size,
                              hipStream_t stream) {
  const int*   x_ids = (const int*)d_in[0];
  const int*   trans = (const int*)d_in[1];
  const float* embed = (const float*)d_in[2];
  const float* Wp    = (const float*)d_in[3];
  const float* bp    = (const float*)d_in[4];
  const float* Wg    = (const float*)d_in[5];
  const float* bg    = (const float*)d_in[6];
  const float* Wr    = (const float*)d_in[7];
  const float* br    = (const float*)d_in[8];
  const float* Wo    = (const float*)d_in[9];
  const float* bo    = (const float*)d_in[10];
  float* out = (float*)d_out;

  float* ws       = (float*)d_ws;
  float* WcT      = ws;                                   // 300*512
  float* W4       = WcT + 300 * 512;                      // 512*1280 (float4-tiled)
  float* states   = W4 + 512 * 1280;                      // buffers[B*T*512] ++ internal[B*NINT*512]
  int*   meta     = (int*)(states + (size_t)IOFF + (size_t)B * NINT * 512);  // B*NINT
  int*   levCnt   = meta + B * NINT;                      // 256
  int*   levOff   = levCnt + 256;                         // 256
  int*   maxLevG  = levOff + 256;                         // 1
  int*   rootA    = maxLevG + 1;                          // B
  unsigned* worklist = (unsigned*)(rootA + B);            // B*NINT
  unsigned* bar   = worklist + B * NINT;                  // BAR_WORDS u32

  k_transpose<<<(5 * HH * 2 * HH + 255) / 256, 256, 0, stream>>>(Wp, Wg, Wr, WcT, W4);
  k_buffers<<<dim3(T / TT, B), 256, 0, stream>>>(x_ids, embed, WcT, bp, bg, states);

  const size_t prep_lds = 65536 + 32640 + (size_t)CHUNK * 128 * 4;   // 147328 B
  k_prep<<<1, 128, prep_lds, stream>>>(trans, meta, levCnt, levOff, maxLevG, rootA,
                                       worklist, bar);

  for (int lev = 1; lev <= LMAX_DIRECT; ++lev) {
    int g = (lev <= 8) ? 512 : (lev <= 24) ? 256 : (lev <= 48) ? 128 : 64;
    k_level<<<g, 256, 0, stream>>>(lev, W4, br, meta, levCnt, levOff, maxLevG,
                                   worklist, states);
  }

  {
    void* args[] = {(void*)&W4, (void*)&br, (void*)&meta, (void*)&levCnt, (void*)&levOff,
                    (void*)&maxLevG, (void*)&worklist, (void*)&states, (void*)&bar};
    hipLaunchCooperativeKernel((void*)k_catchall, dim3(512), dim3(256), args, 0, stream);
  }

  k_out<<<B, 256, 0, stream>>>(Wo, bo, rootA, states, out);
}

// Round 11
// 3512.268 us; speedup vs baseline: 1.7117x; 1.7117x over previous
//
#include <hip/hip_runtime.h>
#include <hip/hip_bf16.h>

// Problem constants
#define B 128
#define T 256
#define E 300
#define HH 256
#define O 5
#define NSTEP (2*T - 1)   // 511
#define NINT 255          // internal (reduce) nodes per batch
#define NG 8              // nodes per group (r10: NG=16 doubled LDS, halved occupancy, -56% perf)
#define PSTR 41           // padded partial stride (5*NG + 1)
#define IOFF 16777216u    // internal[] offset from buffers base (B*T*512)
#define LMAX_DIRECT 176   // per-level launches cover 1..176; catch-all covers rest
#define CHUNK 96          // k_prep trans staging chunk
#define BAR_STRIDE 16
#define BAR_WORDS ((32 + 2) * BAR_STRIDE)

__device__ __forceinline__ float sigm(float x) { return 1.f / (1.f + __expf(-x)); }

// ---------------------------------------------------------------------------
// Hierarchical monotonic grid barrier (catch-all only; normally never runs).
// ---------------------------------------------------------------------------
__device__ __forceinline__ void grid_barrier(unsigned* bar, int myN) {
  __syncthreads();
  if (threadIdx.x == 0) {
    __threadfence();
    const int per_sub = (int)(gridDim.x >> 5);
    const int s = (int)(blockIdx.x & 31);
    unsigned r = atomicAdd(&bar[s * BAR_STRIDE], 1u);
    if (r == (unsigned)(myN * per_sub - 1)) {
      unsigned q = atomicAdd(&bar[32 * BAR_STRIDE], 1u);
      if (q == (unsigned)(myN * 32 - 1)) {
        atomicAdd(&bar[33 * BAR_STRIDE], 1u);
      }
    }
    while (__hip_atomic_load(&bar[33 * BAR_STRIDE], __ATOMIC_ACQUIRE,
                             __HIP_MEMORY_SCOPE_AGENT) < (unsigned)myN) {
      __builtin_amdgcn_s_sleep(2);
    }
    __threadfence();
  }
  __syncthreads();
}

// ---------------------------------------------------------------------------
// K0: weight prep.
//   WcT[e][0:256] = Wp[h][e], WcT[e][256:512] = Wg[h][e]
//   W4: float4-tiled Wr^T:  W4[((k>>2)*1280 + j)*4 + (k&3)] = Wr[j][k]
// ---------------------------------------------------------------------------
__global__ __launch_bounds__(256) void k_transpose(
    const float* __restrict__ Wp, const float* __restrict__ Wg,
    const float* __restrict__ Wr, float* __restrict__ WcT,
    float* __restrict__ W4) {
  int idx = blockIdx.x * 256 + threadIdx.x;
  if (idx < HH * E) {
    int h = idx / E;
    int e = idx % E;
    WcT[e * 512 + h]       = Wp[idx];
    WcT[e * 512 + 256 + h] = Wg[idx];
  }
  if (idx < 5 * HH * 2 * HH) {   // 1280*512
    int j = idx / 512;
    int k = idx % 512;
    W4[((size_t)(k >> 2) * 1280 + j) * 4 + (k & 3)] = Wr[idx];
  }
}

// ---------------------------------------------------------------------------
// K1: leaf states. buffers[b][t][0:256]=h, [256:512]=c
// r10 PMC: 215us, VALUBusy 68% at 46TF -> LDS-issue bound (16 scalar ds_read
// per e). Fix: float4 LDS reads over e-blocks of 4 (E=300 -> 75 float4).
// ---------------------------------------------------------------------------
#define TT 16
__global__ __launch_bounds__(256) void k_buffers(
    const int* __restrict__ x_ids, const float* __restrict__ embed,
    const float* __restrict__ WcT, const float* __restrict__ bp,
    const float* __restrict__ bg, float* __restrict__ buffers) {
  __shared__ __align__(16) float lds[TT * E];
  const int b  = blockIdx.y;
  const int t0 = blockIdx.x * TT;
  const int tid = threadIdx.x;

  for (int i = tid; i < TT * E; i += 256) {
    int t = i / E;
    int e = i % E;
    int id = x_ids[b * T + t0 + t];
    lds[i] = embed[(size_t)id * E + e];
  }
  __syncthreads();

  const int h = tid;
  float accP[TT], accG[TT];
#pragma unroll
  for (int t = 0; t < TT; ++t) { accP[t] = bp[h]; accG[t] = bg[h]; }

  const float4* lds4 = (const float4*)lds;
  for (int e4 = 0; e4 < E / 4; ++e4) {
    const float* wc = WcT + (e4 * 4) * 512 + h;
    float wp0 = wc[0],    wg0 = wc[256];
    float wp1 = wc[512],  wg1 = wc[768];
    float wp2 = wc[1024], wg2 = wc[1280];
    float wp3 = wc[1536], wg3 = wc[1792];
#pragma unroll
    for (int t = 0; t < TT; ++t) {
      float4 x = lds4[t * (E / 4) + e4];
      accP[t] = fmaf(x.x, wp0, accP[t]); accG[t] = fmaf(x.x, wg0, accG[t]);
      accP[t] = fmaf(x.y, wp1, accP[t]); accG[t] = fmaf(x.y, wg1, accG[t]);
      accP[t] = fmaf(x.z, wp2, accP[t]); accG[t] = fmaf(x.z, wg2, accG[t]);
      accP[t] = fmaf(x.w, wp3, accP[t]); accG[t] = fmaf(x.w, wg3, accG[t]);
    }
  }

#pragma unroll
  for (int t = 0; t < TT; ++t) {
    float c  = accP[t];
    float hb = tanhf(c) * sigm(accG[t]);
    size_t base = ((size_t)b * T + t0 + t) * 512;
    buffers[base + h]       = hb;
    buffers[base + 256 + h] = c;
  }
}

// ---------------------------------------------------------------------------
// K2: prep — LDS-resident (r10: dropped out of top-5, keep). 1 block, 128 thr.
// meta[b][r] = left | right<<9 | level<<18
// ---------------------------------------------------------------------------
__global__ __launch_bounds__(128) void k_prep(
    const int* __restrict__ trans, int* __restrict__ meta,
    int* __restrict__ levCnt, int* __restrict__ levOff, int* __restrict__ maxLevG,
    int* __restrict__ rootA, unsigned* __restrict__ worklist,
    unsigned* __restrict__ bar) {
  extern __shared__ char dynls[];
  unsigned short* stkL = (unsigned short*)dynls;                 // [256][128] 64KB
  unsigned char*  levL = (unsigned char*)(dynls + 65536);        // [255][128] 32640B
  int*            tch  = (int*)(dynls + 65536 + 32640);          // [CHUNK][128] 48KB
  __shared__ int cnt[256];
  __shared__ int off[256];
  __shared__ int cur[256];
  const int b = threadIdx.x;
  for (int i = b; i < 256; i += 128) cnt[i] = 0;
  for (int i = b; i < BAR_WORDS; i += 128) bar[i] = 0u;
  __syncthreads();

  int sp = 0, bp = T, r = 0;
  for (int c0 = 0; c0 < NSTEP; c0 += CHUNK) {
    const int cend = min(NSTEP - c0, CHUNK);
    __syncthreads();                         // prior chunk consumed
    for (int i = b; i < cend * 128; i += 128) tch[i] = trans[c0 * 128 + i];
    __syncthreads();
    for (int s = 0; s < cend; ++s) {
      int tr = tch[s * 128 + b];
      if (tr == 0) {                         // SHIFT
        stkL[sp * 128 + b] = (unsigned short)(bp - 1);
        sp++; bp--;
      } else {                               // REDUCE
        int idR = stkL[(sp - 1) * 128 + b];
        int idL = stkL[(sp - 2) * 128 + b];
        sp -= 2;
        int lL = (idL < 256) ? 0 : (int)levL[(idL - 256) * 128 + b];
        int lR = (idR < 256) ? 0 : (int)levL[(idR - 256) * 128 + b];
        int lev = max(lL, lR) + 1;
        levL[r * 128 + b] = (unsigned char)lev;
        meta[b * NINT + r] = idL | (idR << 9) | (lev << 18);   // fire-and-forget
        atomicAdd(&cnt[lev], 1);
        stkL[sp * 128 + b] = (unsigned short)(256 + r);
        sp++; r++;
      }
    }
  }
  rootA[b] = (int)stkL[0 * 128 + b];
  __syncthreads();

  if (b == 0) {
    int acc = 0, ml = 1;
    for (int l = 0; l < 256; ++l) {
      off[l] = acc; acc += cnt[l];
      if (cnt[l] > 0) ml = l;
    }
    *maxLevG = ml;
  }
  __syncthreads();
  for (int i = b; i < 256; i += 128) { levCnt[i] = cnt[i]; levOff[i] = off[i]; cur[i] = off[i]; }
  __syncthreads();

  for (int i = 0; i < NINT; ++i) {
    int lev = (int)levL[i * 128 + b];
    int pos = atomicAdd(&cur[lev], 1);
    worklist[pos] = (unsigned)((b << 9) | (256 + i));
  }
}

// ---------------------------------------------------------------------------
// Level body. NG=8 (occupancy-optimal per r8 vs r10 A/B).
// Item = (group, 64-col h-slice); thread (hcol=tid&63, kq=tid>>6).
// States addressed as u32 dword offsets from `states` base.
// ---------------------------------------------------------------------------
__device__ __forceinline__ void do_level(
    int cnt, int woff,
    const float* __restrict__ W4, const float* __restrict__ br,
    const int* __restrict__ meta, const unsigned* __restrict__ worklist,
    float* __restrict__ states, float* smem) {
  const int tid  = threadIdx.x;
  const int hcol = tid & 63;
  const int kq   = tid >> 6;

  const int ngrp = (cnt + NG - 1) / NG;
  const int items = ngrp << 2;

  for (int item = blockIdx.x; item < items; item += gridDim.x) {
    const int grp = item >> 2;
    const int h0  = (item & 3) << 6;
    __syncthreads();   // prior item's LDS reads complete before restage

    // --- node meta -> uniform u32 state offsets (SGPRs) ---
    unsigned offL[NG], offR[NG], offD[NG];
#pragma unroll
    for (int n = 0; n < NG; ++n) {
      int wi = woff + grp * NG + n;
      if (wi >= woff + cnt) wi = woff + cnt - 1;     // pad: duplicate last node
      unsigned w = worklist[wi];
      int node = __builtin_amdgcn_readfirstlane((int)(w & 511u));
      int bb   = __builtin_amdgcn_readfirstlane((int)(w >> 9));
      int m    = __builtin_amdgcn_readfirstlane(meta[bb * NINT + node - 256]);
      int il = m & 511, ir = (m >> 9) & 511;
      offL[n] = (il < 256) ? ((unsigned)(bb * T + il) << 9)
                           : (IOFF + ((unsigned)(bb * NINT + il - 256) << 9));
      offR[n] = (ir < 256) ? ((unsigned)(bb * T + ir) << 9)
                           : (IOFF + ((unsigned)(bb * NINT + ir - 256) << 9));
      offD[n] = IOFF + ((unsigned)(bb * NINT + node - 256) << 9);
    }

    // --- stage x = [hl | hr] into LDS (coalesced) ---
    float* xs = smem;                                // [NG][512]
#pragma unroll
    for (int n = 0; n < NG; ++n) {
      xs[n * 512 + tid]       = states[(size_t)offL[n] + tid];
      xs[n * 512 + 256 + tid] = states[(size_t)offR[n] + tid];
    }
    __syncthreads();

    // --- FMA over this thread's k-quarter (coalesced float4 weights) ---
    float a0[NG], a1[NG], a2[NG], a3[NG], a4[NG];
#pragma unroll
    for (int n = 0; n < NG; ++n) { a0[n]=0.f; a1[n]=0.f; a2[n]=0.f; a3[n]=0.f; a4[n]=0.f; }

    const float4* W4v = (const float4*)W4;
    const int jb = h0 + hcol;
    const int k4end = (kq << 5) + 32;
    for (int k4 = kq << 5; k4 < k4end; ++k4) {       // k = 4*k4
      const size_t kb4 = (size_t)k4 * 1280 + jb;
      float4 w0 = W4v[kb4];
      float4 w1 = W4v[kb4 + 256];
      float4 w2 = W4v[kb4 + 512];
      float4 w3 = W4v[kb4 + 768];
      float4 w4 = W4v[kb4 + 1024];
#pragma unroll
      for (int n = 0; n < NG; ++n) {
        float4 xv = *(const float4*)&xs[n * 512 + (k4 << 2)];
        float s0 = a0[n], s1 = a1[n], s2 = a2[n], s3 = a3[n], s4 = a4[n];
        s0 = fmaf(w0.x, xv.x, s0); s0 = fmaf(w0.y, xv.y, s0);
        s0 = fmaf(w0.z, xv.z, s0); s0 = fmaf(w0.w, xv.w, s0);
        s1 = fmaf(w1.x, xv.x, s1); s1 = fmaf(w1.y, xv.y, s1);
        s1 = fmaf(w1.z, xv.z, s1); s1 = fmaf(w1.w, xv.w, s1);
        s2 = fmaf(w2.x, xv.x, s2); s2 = fmaf(w2.y, xv.y, s2);
        s2 = fmaf(w2.z, xv.z, s2); s2 = fmaf(w2.w, xv.w, s2);
        s3 = fmaf(w3.x, xv.x, s3); s3 = fmaf(w3.y, xv.y, s3);
        s3 = fmaf(w3.z, xv.z, s3); s3 = fmaf(w3.w, xv.w, s3);
        s4 = fmaf(w4.x, xv.x, s4); s4 = fmaf(w4.y, xv.y, s4);
        s4 = fmaf(w4.z, xv.z, s4); s4 = fmaf(w4.w, xv.w, s4);
        a0[n] = s0; a1[n] = s1; a2[n] = s2; a3[n] = s3; a4[n] = s4;
      }
    }
    __syncthreads();   // xs dead; smem becomes partial buffer

    // --- k-split reduce: kq>=1 deposit partials ---
    if (kq >= 1) {
      float* pp = smem + (kq - 1) * (64 * PSTR) + hcol * PSTR;
#pragma unroll
      for (int n = 0; n < NG; ++n) {
        pp[n]          = a0[n];
        pp[NG + n]     = a1[n];
        pp[2 * NG + n] = a2[n];
        pp[3 * NG + n] = a3[n];
        pp[4 * NG + n] = a4[n];
      }
    }
    __syncthreads();

    // --- combine: kq==0 finishes its column for all NG nodes ---
    if (kq == 0) {
      const int habs = h0 + hcol;
      const float b0 = br[habs];
      const float b1 = br[256 + habs];
      const float b2 = br[512 + habs];
      const float b3 = br[768 + habs];
      const float b4 = br[1024 + habs];
#pragma unroll
      for (int n = 0; n < NG; ++n) {
        const float* q0 = smem + 0 * (64 * PSTR) + hcol * PSTR;
        const float* q1 = smem + 1 * (64 * PSTR) + hcol * PSTR;
        const float* q2 = smem + 2 * (64 * PSTR) + hcol * PSTR;
        float p0 = a0[n] + q0[n]          + q1[n]          + q2[n]          + b0;
        float p1 = a1[n] + q0[NG + n]     + q1[NG + n]     + q2[NG + n]     + b1;
        float p2 = a2[n] + q0[2 * NG + n] + q1[2 * NG + n] + q2[2 * NG + n] + b2;
        float p3 = a3[n] + q0[3 * NG + n] + q1[3 * NG + n] + q2[3 * NG + n] + b3;
        float p4 = a4[n] + q0[4 * NG + n] + q1[4 * NG + n] + q2[4 * NG + n] + b4;
        float cl = states[(size_t)offL[n] + 256 + habs];
        float cr = states[(size_t)offR[n] + 256 + habs];
        float ci  = sigm(p0);
        float cfl = sigm(p1);
        float cfr = sigm(p2);
        float tg  = tanhf(p3);
        float co  = sigm(p4);
        float cn  = ci * tg + cfl * cl + cfr * cr;
        float hn  = co * tanhf(cn);
        states[(size_t)offD[n] + habs]       = hn;   // dup-pad rewrites same value
        states[(size_t)offD[n] + 256 + habs] = cn;
      }
    }
  }
}

// ---------------------------------------------------------------------------
// K3a: one launch per level. Levels beyond maxLev exit immediately.
// launch_bounds(256,4): 4 blocks/CU (LDS 31.5KB allows 5; VGPR capped 128).
// ---------------------------------------------------------------------------
__global__ __launch_bounds__(256, 4) void k_level(
    int lev, const float* __restrict__ W4, const float* __restrict__ br,
    const int* __restrict__ meta, const int* __restrict__ levCnt,
    const int* __restrict__ levOff, const int* __restrict__ maxLevG,
    const unsigned* __restrict__ worklist, float* __restrict__ states) {
  __shared__ float smem[3 * 64 * PSTR];   // 31488 B (union: xs 16KB / partials)
  if (lev > *maxLevG) return;
  const int cnt = levCnt[lev];
  if (cnt == 0) return;
  do_level(cnt, levOff[lev], W4, br, meta, worklist, states, smem);
}

// ---------------------------------------------------------------------------
// K3b: cooperative catch-all for levels LMAX_DIRECT+1..maxLev (normally a
// no-op: expected maxLev ~100-120 < 176).
// ---------------------------------------------------------------------------
__global__ __launch_bounds__(256, 2) void k_catchall(
    const float* __restrict__ W4, const float* __restrict__ br,
    const int* __restrict__ meta, const int* __restrict__ levCnt,
    const int* __restrict__ levOff, const int* __restrict__ maxLevG,
    const unsigned* __restrict__ worklist, float* __restrict__ states,
    unsigned* __restrict__ bar) {
  __shared__ float smem[3 * 64 * PSTR];
  const int maxLev = *maxLevG;
  if (maxLev <= LMAX_DIRECT) return;
  for (int lev = LMAX_DIRECT + 1; lev <= maxLev; ++lev) {
    do_level(levCnt[lev], levOff[lev], W4, br, meta, worklist, states, smem);
    grid_barrier(bar, lev - LMAX_DIRECT);
  }
}

// ---------------------------------------------------------------------------
// K4: logits = root_h @ Wo^T + bo
// ---------------------------------------------------------------------------
__global__ __launch_bounds__(256) void k_out(
    const float* __restrict__ Wo, const float* __restrict__ bo,
    const int* __restrict__ rootA, const float* __restrict__ states,
    float* __restrict__ out) {
  const int b = blockIdx.x;
  const int tid = threadIdx.x;
  __shared__ float red[256];
  int rid = rootA[b];
  unsigned hoff = (rid < 256) ? ((unsigned)(b * T + rid) << 9)
                              : (IOFF + ((unsigned)(b * NINT + rid - 256) << 9));
  float hj = states[(size_t)hoff + tid];
  for (int m = 0; m < O; ++m) {
    red[tid] = Wo[m * HH + tid] * hj;
    __syncthreads();
    for (int off = 128; off > 0; off >>= 1) {
      if (tid < off) red[tid] += red[tid + off];
      __syncthreads();
    }
    if (tid == 0) out[b * O + m] = red[0] + bo[m];
    __syncthreads();
  }
}

// ---------------------------------------------------------------------------
extern "C" void kernel_launch(void* const* d_in, const int* in_sizes, int n_in,
                              void* d_out, int out_size, void* d_ws, size_t ws_size,
                              hipStream_t stream) {
  const int*   x_ids = (const int*)d_in[0];
  const int*   trans = (const int*)d_in[1];
  const float* embed = (const float*)d_in[2];
  const float* Wp    = (const float*)d_in[3];
  const float* bp    = (const float*)d_in[4];
  const float* Wg    = (const float*)d_in[5];
  const float* bg    = (const float*)d_in[6];
  const float* Wr    = (const float*)d_in[7];
  const float* br    = (const float*)d_in[8];
  const float* Wo    = (const float*)d_in[9];
  const float* bo    = (const float*)d_in[10];
  float* out = (float*)d_out;

  float* ws       = (float*)d_ws;
  float* WcT      = ws;                                   // 300*512
  float* W4       = WcT + 300 * 512;                      // 512*1280 (float4-tiled)
  float* states   = W4 + 512 * 1280;                      // buffers[B*T*512] ++ internal[B*NINT*512]
  int*   meta     = (int*)(states + (size_t)IOFF + (size_t)B * NINT * 512);  // B*NINT
  int*   levCnt   = meta + B * NINT;                      // 256
  int*   levOff   = levCnt + 256;                         // 256
  int*   maxLevG  = levOff + 256;                         // 1
  int*   rootA    = maxLevG + 1;                          // B
  unsigned* worklist = (unsigned*)(rootA + B);            // B*NINT
  unsigned* bar   = worklist + B * NINT;                  // BAR_WORDS u32

  k_transpose<<<(5 * HH * 2 * HH + 255) / 256, 256, 0, stream>>>(Wp, Wg, Wr, WcT, W4);
  k_buffers<<<dim3(T / TT, B), 256, 0, stream>>>(x_ids, embed, WcT, bp, bg, states);

  const size_t prep_lds = 65536 + 32640 + (size_t)CHUNK * 128 * 4;   // 147328 B
  k_prep<<<1, 128, prep_lds, stream>>>(trans, meta, levCnt, levOff, maxLevG, rootA,
                                       worklist, bar);

  for (int lev = 1; lev <= LMAX_DIRECT; ++lev) {
    int g = (lev <= 16) ? 512 : (lev <= 48) ? 256 : 128;
    k_level<<<g, 256, 0, stream>>>(lev, W4, br, meta, levCnt, levOff, maxLevG,
                                   worklist, states);
  }

  {
    void* args[] = {(void*)&W4, (void*)&br, (void*)&meta, (void*)&levCnt, (void*)&levOff,
                    (void*)&maxLevG, (void*)&worklist, (void*)&states, (void*)&bar};
    hipLaunchCooperativeKernel((void*)k_catchall, dim3(512), dim3(256), args, 0, stream);
  }

  k_out<<<B, 256, 0, stream>>>(Wo, bo, rootA, states, out);
}